// Round 5
// baseline (330.669 us; speedup 1.0000x reference)
//
#include <hip/hip_runtime.h>

#define L1_BINS 8192          // top 13 bits of 22-bit fixed-point key
#define L2_BINS 512           // low 9 bits
#define KEY_MAX 4194303u      // 2^22 - 1
#define NH2_BLOCKS 512
#define NREF_BLOCKS 512
#define NBIN_BLOCKS 256

struct Ranks { unsigned int r[32]; };
struct Fracs { float f[16]; };

// ---------------- Zero merged hist + hist2 + done-counter -----------------
__global__ __launch_bounds__(256) void k_zero(uint4* __restrict__ p, int n4) {
  int i = blockIdx.x * blockDim.x + threadIdx.x;
  if (i < n4) p[i] = make_uint4(0u, 0u, 0u, 0u);
}

// ---------------- Kernel A: 4 lanes/row, coalesced; LDS hist -> global ----
__global__ __launch_bounds__(256) void k_h2(const float* __restrict__ logits,
                                            const int* __restrict__ labels,
                                            unsigned int* __restrict__ keys,
                                            unsigned int* __restrict__ merged,
                                            int n) {
  __shared__ unsigned int lh[L1_BINS];
  for (int i = threadIdx.x; i < L1_BINS; i += blockDim.x) lh[i] = 0u;
  __syncthreads();
  int tid = blockIdx.x * blockDim.x + threadIdx.x;
  int sub = tid & 3;
  int group = tid >> 2;
  int ngroups = (gridDim.x * blockDim.x) >> 2;
  for (int row = group; row < n; row += ngroups) {
    float4 v = reinterpret_cast<const float4*>(logits)[(size_t)row * 4 + sub];
    // local max + first-argmax over this lane's 4 classes
    float m = v.x; int a = 0;
    if (v.y > m) { m = v.y; a = 1; }
    if (v.z > m) { m = v.z; a = 2; }
    if (v.w > m) { m = v.w; a = 3; }
    int gidx = sub * 4 + a;
    // 4-lane group max with first-max tiebreak (masks 1,2 stay in group)
#pragma unroll
    for (int mask = 1; mask <= 2; mask <<= 1) {
      float om = __shfl_xor(m, mask);
      int oi = __shfl_xor(gidx, mask);
      if (om > m || (om == m && oi < gidx)) { m = om; gidx = oi; }
    }
    float e0 = __expf(v.x - m), e1 = __expf(v.y - m);
    float e2 = __expf(v.z - m), e3 = __expf(v.w - m);
    float Z = e0 + e1 + e2 + e3;
    float S2 = e0 * e0 + e1 * e1 + e2 * e2 + e3 * e3;
#pragma unroll
    for (int mask = 1; mask <= 2; mask <<= 1) {
      Z += __shfl_xor(Z, mask);
      S2 += __shfl_xor(S2, mask);
    }
    if (sub == 0) {
      float r = S2 / (Z * Z) + 1e-12f;
      float h2 = -__log2f(r);
      int ki = (int)(h2 * 1048576.0f);
      unsigned int key = (unsigned int)min(max(ki, 0), (int)KEY_MAX);
      unsigned int err = (gidx != labels[row]) ? 0x80000000u : 0u;
      keys[row] = key | err;
      atomicAdd(&lh[key >> 9], 1u);
    }
  }
  __syncthreads();
  // flush block hist into single global hist (coalesced-adjacent atomics)
  for (int i = threadIdx.x; i < L1_BINS; i += blockDim.x) {
    unsigned int v = lh[i];
    if (v) atomicAdd(&merged[i], v);
  }
}

// ---------------- Wave-cooperative rank selection on a histogram ----------
__global__ void k_select(const unsigned int* __restrict__ hist,
                         unsigned int* __restrict__ selpfx,
                         unsigned int* __restrict__ selrank,
                         float* __restrict__ vout,
                         int nb, int perq, int shift, int last, int first,
                         Ranks rk) {
  int j = blockIdx.x;
  int lane = threadIdx.x;
  const unsigned int* h = hist + (perq ? (size_t)j * (size_t)nb : (size_t)0);
  unsigned int rem = first ? rk.r[j] : selrank[j];
  int base = 0, len = nb;
  while (len > 64) {
    int chunk = (len + 63) >> 6;
    int start = base + lane * chunk;
    int end = base + len;
    unsigned int s = 0;
    for (int t = 0; t < chunk; ++t) {
      int idx = start + t;
      if (idx < end) s += h[idx];
    }
    unsigned int inc = s;
#pragma unroll
    for (int d = 1; d < 64; d <<= 1) {
      unsigned int u = __shfl_up(inc, d);
      if (lane >= d) inc += u;
    }
    unsigned int ex = inc - s;
    bool own = (rem >= ex) && (rem < ex + s);
    unsigned long long bal = __ballot(own);
    int src = __ffsll((long long)bal) - 1;
    unsigned int exs = __shfl(ex, src);
    int nbase = base + src * chunk;
    len = min(chunk, end - nbase);
    base = nbase;
    rem -= exs;
  }
  unsigned int s = (lane < len) ? h[base + lane] : 0u;
  unsigned int inc = s;
#pragma unroll
  for (int d = 1; d < 64; d <<= 1) {
    unsigned int u = __shfl_up(inc, d);
    if (lane >= d) inc += u;
  }
  unsigned int ex = inc - s;
  bool own = (rem >= ex) && (rem < ex + s);
  unsigned long long bal = __ballot(own);
  int src = __ffsll((long long)bal) - 1;
  unsigned int exs = __shfl(ex, src);
  if (lane == 0) {
    unsigned int idx = (unsigned int)(base + src);
    unsigned int pfx = first ? idx : ((selpfx[j] << shift) | idx);
    selpfx[j] = pfx;
    selrank[j] = rem - exs;
    if (last) vout[j] = __uint_as_float(pfx);  // final 22-bit key
  }
}

// ---------------- Refine: sub-hist (low 9 bits) for selected L1 buckets ---
__global__ __launch_bounds__(256) void k_refine(const unsigned int* __restrict__ keys,
                                                const unsigned int* __restrict__ selpfx,
                                                unsigned int* __restrict__ hist2,
                                                int n) {
  __shared__ unsigned int sp[32];
  if (threadIdx.x < 32) sp[threadIdx.x] = selpfx[threadIdx.x];
  __syncthreads();
  int stride = gridDim.x * blockDim.x;
  for (int i = blockIdx.x * blockDim.x + threadIdx.x; i < n; i += stride) {
    unsigned int key = keys[i] & KEY_MAX;
    unsigned int hi = key >> 9;
    unsigned int sub = key & (L2_BINS - 1);
#pragma unroll
    for (int jj = 0; jj < 32; ++jj) {
      if (hi == sp[jj]) atomicAdd(&hist2[jj * L2_BINS + (int)sub], 1u);
    }
  }
}

// ---------------- Binning pass + fused final (last-block reduction) -------
__global__ __launch_bounds__(256) void k_bin(const unsigned int* __restrict__ keys,
                                             const float* __restrict__ vp,
                                             float* __restrict__ partials,
                                             unsigned int* __restrict__ done,
                                             float* __restrict__ out, int n,
                                             Fracs fr) {
  __shared__ float sedge[16];
  __shared__ float swacc[4][48];
  __shared__ unsigned int is_last;
  if (threadIdx.x < 16) {
    int i = threadIdx.x;
    unsigned int klo = __float_as_uint(vp[2 * i]);
    unsigned int khi = __float_as_uint(vp[2 * i + 1]);
    float lo = (float)(klo + 1u) * 0x1p-20f;   // upper boundary of bin (exact)
    float hi = (float)(khi + 1u) * 0x1p-20f;
    float f = fr.f[i];
    float e = lo * (1.0f - f) + hi * f;
    if (i == 15) e += 1e-6f;
    sedge[i] = e;
  }
  __syncthreads();
  float e[16];
#pragma unroll
  for (int j = 0; j < 16; ++j) e[j] = sedge[j];
  float cnt[15], sH[15], sE[15];
#pragma unroll
  for (int b = 0; b < 15; ++b) { cnt[b] = 0.f; sH[b] = 0.f; sE[b] = 0.f; }
  int stride = gridDim.x * blockDim.x;
  for (int i = blockIdx.x * blockDim.x + threadIdx.x; i < n; i += stride) {
    unsigned int kp = keys[i];
    float h = ((float)(kp & KEY_MAX) + 0.5f) * 0x1p-20f;
    float er = (kp & 0x80000000u) ? 1.0f : 0.0f;
    int less = 0;
#pragma unroll
    for (int j = 0; j < 16; ++j) less += (h > e[j]) ? 1 : 0;
    int bin = less - 1;  // valid bins 0..14
#pragma unroll
    for (int b = 0; b < 15; ++b) {
      bool m = (bin == b);
      cnt[b] += m ? 1.f : 0.f;
      sH[b] += m ? h : 0.f;
      sE[b] += m ? er : 0.f;
    }
  }
  int wid = threadIdx.x >> 6;
  int lane = threadIdx.x & 63;
#pragma unroll
  for (int b = 0; b < 15; ++b) {
    float c = cnt[b], a = sH[b], s = sE[b];
    for (int off = 32; off > 0; off >>= 1) {
      c += __shfl_xor(c, off);
      a += __shfl_xor(a, off);
      s += __shfl_xor(s, off);
    }
    if (lane == 0) {
      swacc[wid][b] = c;
      swacc[wid][15 + b] = a;
      swacc[wid][30 + b] = s;
    }
  }
  __syncthreads();
  if (threadIdx.x < 45) {
    int v = threadIdx.x;
    float s = swacc[0][v] + swacc[1][v] + swacc[2][v] + swacc[3][v];
    partials[v * NBIN_BLOCKS + blockIdx.x] = s;
  }
  // ---- last block performs the final reduction ----
  __threadfence();
  if (threadIdx.x == 0)
    is_last = (atomicAdd(done, 1u) == (unsigned int)gridDim.x - 1u) ? 1u : 0u;
  __syncthreads();
  if (is_last && threadIdx.x < 64) {
    __shared__ float sacc[45];
    int l = threadIdx.x;
    for (int v = 0; v < 45; ++v) {
      float s = 0.f;
      for (int b = l; b < NBIN_BLOCKS; b += 64) s += partials[v * NBIN_BLOCKS + b];
      for (int off = 32; off > 0; off >>= 1) s += __shfl_xor(s, off);
      if (l == 0) sacc[v] = s;
    }
    __builtin_amdgcn_s_barrier();  // single wave; harmless
    float g = 0.f;
    if (l < 15) {
      float c = sacc[l], sh = sacc[15 + l], se = sacc[30 + l];
      float safe = fmaxf(c, 1.f);
      float u = sh / safe, eb = se / safe;
      float inner = 2.0f * exp2f(-u) - 1.0f;
      float s = (inner > 0.f) ? sqrtf(inner) : 0.f;
      float risk = 0.5f * (1.0f - s);
      g = (c > 0.f) ? fabsf(eb - risk) : 0.f;
    }
    for (int off = 32; off > 0; off >>= 1) g += __shfl_xor(g, off);
    if (l == 0) out[0] = g * (1.0f / 15.0f);
  }
}

extern "C" void kernel_launch(void* const* d_in, const int* in_sizes, int n_in,
                              void* d_out, int out_size, void* d_ws, size_t ws_size,
                              hipStream_t stream) {
  const float* logits = (const float*)d_in[0];
  const int* labels = (const int*)d_in[1];
  float* out = (float*)d_out;
  int n = in_sizes[1];  // labels count = number of rows

  char* ws = (char*)d_ws;
  size_t offKeys = 0;                                   // n*4
  size_t offMerged = (size_t)n * 4;                     // 8192*4   (zeroed)
  size_t offH2b = offMerged + (size_t)L1_BINS * 4;      // 32*512*4 (zeroed)
  size_t offDone = offH2b + 32 * L2_BINS * 4;           // 16 B     (zeroed)
  size_t zeroEnd = offDone + 16;
  size_t offSelP = zeroEnd;                             // 32*4
  size_t offSelR = offSelP + 128;                       // 32*4
  size_t offV = offSelR + 128;                          // 32*4
  size_t offPart = (offV + 128 + 255) & ~(size_t)255;   // 45*NBIN_BLOCKS*4

  unsigned int* keys = (unsigned int*)(ws + offKeys);
  unsigned int* merged = (unsigned int*)(ws + offMerged);
  unsigned int* hist2 = (unsigned int*)(ws + offH2b);
  unsigned int* done = (unsigned int*)(ws + offDone);
  unsigned int* selp = (unsigned int*)(ws + offSelP);
  unsigned int* selr = (unsigned int*)(ws + offSelR);
  float* vp = (float*)(ws + offV);
  float* part = (float*)(ws + offPart);

  // host-side quantile positions (f32, matching jnp.linspace/quantile math)
  Ranks rk;
  Fracs fr;
  float nm1 = (float)(n - 1);
  for (int i = 0; i < 16; ++i) {
    float q = (i == 15) ? 1.0f : (float)i * (1.0f / 15.0f);
    float idxf = q * nm1;
    float flo = floorf(idxf);
    unsigned int klo = (unsigned int)flo;
    unsigned int khi = (unsigned int)ceilf(idxf);
    unsigned int maxi = (unsigned int)(n - 1);
    if (klo > maxi) klo = maxi;
    if (khi > maxi) khi = maxi;
    rk.r[2 * i] = klo;
    rk.r[2 * i + 1] = khi;
    fr.f[i] = idxf - flo;
  }

  // 0) zero merged hist + hist2 + done counter (~96KB)
  int zero4 = (int)((zeroEnd - offMerged) >> 4);
  k_zero<<<(zero4 + 255) / 256, 256, 0, stream>>>((uint4*)(ws + offMerged), zero4);
  // 1) H2 -> packed keys + global L1 hist (coalesced 4-lane/row)
  k_h2<<<NH2_BLOCKS, 256, 0, stream>>>(logits, labels, keys, merged, n);
  // 2) select L1 bucket (13 bits) for each of 32 ranks
  k_select<<<32, 64, 0, stream>>>(merged, selp, selr, vp, L1_BINS, 0, 0, 0, 1, rk);
  // 3) refine low 9 bits
  k_refine<<<NREF_BLOCKS, 256, 0, stream>>>(keys, selp, hist2, n);
  k_select<<<32, 64, 0, stream>>>(hist2, selp, selr, vp, L2_BINS, 1, 9, 1, 0, rk);
  // 4) binning accumulation + fused final reduction
  k_bin<<<NBIN_BLOCKS, 256, 0, stream>>>(keys, vp, part, done, out, n, fr);

  (void)n_in; (void)out_size; (void)ws_size;
}

// Round 6
// 317.117 us; speedup vs baseline: 1.0427x; 1.0427x over previous
//
#include <hip/hip_runtime.h>

#define L1_BINS 8192          // top 13 bits of 22-bit fixed-point key
#define L2_BINS 512           // low 9 bits
#define KEY_MAX 4194303u      // 2^22 - 1
#define NH2_BLOCKS 1280       // 5 blocks/CU (32KB LDS each) = 20 waves/CU
#define NREF_BLOCKS 512
#define NBIN_BLOCKS 256

struct Ranks { unsigned int r[32]; };
struct Fracs { float f[16]; };

// ---------------- Zero hist2 + done-counter -------------------------------
__global__ __launch_bounds__(256) void k_zero(uint4* __restrict__ p, int n4) {
  int i = blockIdx.x * blockDim.x + threadIdx.x;
  if (i < n4) p[i] = make_uint4(0u, 0u, 0u, 0u);
}

// ---------------- Kernel A: 4 lanes/row coalesced; plain-store hist flush --
__global__ __launch_bounds__(256) void k_h2(const float* __restrict__ logits,
                                            const int* __restrict__ labels,
                                            unsigned int* __restrict__ keys,
                                            unsigned int* __restrict__ histg,
                                            int n) {
  __shared__ unsigned int lh[L1_BINS];
  for (int i = threadIdx.x; i < L1_BINS; i += blockDim.x) lh[i] = 0u;
  __syncthreads();
  int tid = blockIdx.x * blockDim.x + threadIdx.x;
  int sub = tid & 3;
  int group = tid >> 2;
  int ngroups = (gridDim.x * blockDim.x) >> 2;
  for (int row = group; row < n; row += ngroups) {
    float4 v = reinterpret_cast<const float4*>(logits)[(size_t)row * 4 + sub];
    // local max + first-argmax over this lane's 4 classes
    float m = v.x; int a = 0;
    if (v.y > m) { m = v.y; a = 1; }
    if (v.z > m) { m = v.z; a = 2; }
    if (v.w > m) { m = v.w; a = 3; }
    int gidx = sub * 4 + a;
    // 4-lane group max with first-max tiebreak (masks 1,2 stay in group)
#pragma unroll
    for (int mask = 1; mask <= 2; mask <<= 1) {
      float om = __shfl_xor(m, mask);
      int oi = __shfl_xor(gidx, mask);
      if (om > m || (om == m && oi < gidx)) { m = om; gidx = oi; }
    }
    float e0 = __expf(v.x - m), e1 = __expf(v.y - m);
    float e2 = __expf(v.z - m), e3 = __expf(v.w - m);
    float Z = e0 + e1 + e2 + e3;
    float S2 = e0 * e0 + e1 * e1 + e2 * e2 + e3 * e3;
#pragma unroll
    for (int mask = 1; mask <= 2; mask <<= 1) {
      Z += __shfl_xor(Z, mask);
      S2 += __shfl_xor(S2, mask);
    }
    if (sub == 0) {
      float r = S2 / (Z * Z) + 1e-12f;
      float h2 = -__log2f(r);
      int ki = (int)(h2 * 1048576.0f);
      unsigned int key = (unsigned int)min(max(ki, 0), (int)KEY_MAX);
      unsigned int err = (gidx != labels[row]) ? 0x80000000u : 0u;
      keys[row] = key | err;
      atomicAdd(&lh[key >> 9], 1u);
    }
  }
  __syncthreads();
  // plain coalesced flush: pack two adjacent bins per uint (counts <= 16K)
  unsigned int* dst = histg + (size_t)blockIdx.x * (L1_BINS / 2);
  for (int i = threadIdx.x; i < L1_BINS / 2; i += blockDim.x)
    dst[i] = (lh[2 * i] & 0xFFFFu) | (lh[2 * i + 1] << 16);
}

// ---------------- Merge per-block hists (256 blocks, 16 pair-cols each) ---
__global__ __launch_bounds__(256) void k_merge(const unsigned int* __restrict__ histg,
                                               unsigned int* __restrict__ merged,
                                               int nrows) {
  __shared__ unsigned int slo[16][17], shi[16][17];
  int col0 = blockIdx.x * 16;
  int c = threadIdx.x & 15;
  int rg = threadIdx.x >> 4;  // 16 row groups
  unsigned int alo = 0, ahi = 0;
  for (int r = rg; r < nrows; r += 16) {
    unsigned int v = histg[(size_t)r * (L1_BINS / 2) + col0 + c];
    alo += v & 0xFFFFu;
    ahi += v >> 16;
  }
  slo[rg][c] = alo;
  shi[rg][c] = ahi;
  __syncthreads();
  if (threadIdx.x < 16) {
    unsigned int lo = 0, hi = 0;
#pragma unroll
    for (int g = 0; g < 16; ++g) { lo += slo[g][threadIdx.x]; hi += shi[g][threadIdx.x]; }
    int pc = col0 + threadIdx.x;
    merged[2 * pc] = lo;
    merged[2 * pc + 1] = hi;
  }
}

// ---------------- Wave-cooperative rank selection on a histogram ----------
__global__ void k_select(const unsigned int* __restrict__ hist,
                         unsigned int* __restrict__ selpfx,
                         unsigned int* __restrict__ selrank,
                         float* __restrict__ vout,
                         int nb, int perq, int shift, int last, int first,
                         Ranks rk) {
  int j = blockIdx.x;
  int lane = threadIdx.x;
  const unsigned int* h = hist + (perq ? (size_t)j * (size_t)nb : (size_t)0);
  unsigned int rem = first ? rk.r[j] : selrank[j];
  int base = 0, len = nb;
  while (len > 64) {
    int chunk = (len + 63) >> 6;
    int start = base + lane * chunk;
    int end = base + len;
    unsigned int s = 0;
    for (int t = 0; t < chunk; ++t) {
      int idx = start + t;
      if (idx < end) s += h[idx];
    }
    unsigned int inc = s;
#pragma unroll
    for (int d = 1; d < 64; d <<= 1) {
      unsigned int u = __shfl_up(inc, d);
      if (lane >= d) inc += u;
    }
    unsigned int ex = inc - s;
    bool own = (rem >= ex) && (rem < ex + s);
    unsigned long long bal = __ballot(own);
    int src = __ffsll((long long)bal) - 1;
    unsigned int exs = __shfl(ex, src);
    int nbase = base + src * chunk;
    len = min(chunk, end - nbase);
    base = nbase;
    rem -= exs;
  }
  unsigned int s = (lane < len) ? h[base + lane] : 0u;
  unsigned int inc = s;
#pragma unroll
  for (int d = 1; d < 64; d <<= 1) {
    unsigned int u = __shfl_up(inc, d);
    if (lane >= d) inc += u;
  }
  unsigned int ex = inc - s;
  bool own = (rem >= ex) && (rem < ex + s);
  unsigned long long bal = __ballot(own);
  int src = __ffsll((long long)bal) - 1;
  unsigned int exs = __shfl(ex, src);
  if (lane == 0) {
    unsigned int idx = (unsigned int)(base + src);
    unsigned int pfx = first ? idx : ((selpfx[j] << shift) | idx);
    selpfx[j] = pfx;
    selrank[j] = rem - exs;
    if (last) vout[j] = __uint_as_float(pfx);  // final 22-bit key
  }
}

// ---------------- Refine: sub-hist (low 9 bits) for selected L1 buckets ---
__global__ __launch_bounds__(256) void k_refine(const unsigned int* __restrict__ keys,
                                                const unsigned int* __restrict__ selpfx,
                                                unsigned int* __restrict__ hist2,
                                                int n) {
  __shared__ unsigned int sp[32];
  if (threadIdx.x < 32) sp[threadIdx.x] = selpfx[threadIdx.x];
  __syncthreads();
  int stride = gridDim.x * blockDim.x;
  for (int i = blockIdx.x * blockDim.x + threadIdx.x; i < n; i += stride) {
    unsigned int key = keys[i] & KEY_MAX;
    unsigned int hi = key >> 9;
    unsigned int sub = key & (L2_BINS - 1);
#pragma unroll
    for (int jj = 0; jj < 32; ++jj) {
      if (hi == sp[jj]) atomicAdd(&hist2[jj * L2_BINS + (int)sub], 1u);
    }
  }
}

// ---------------- Binning pass + fused final (last-block reduction) -------
__global__ __launch_bounds__(256) void k_bin(const unsigned int* __restrict__ keys,
                                             const float* __restrict__ vp,
                                             float* __restrict__ partials,
                                             unsigned int* __restrict__ done,
                                             float* __restrict__ out, int n,
                                             Fracs fr) {
  __shared__ float sedge[16];
  __shared__ float swacc[4][48];
  __shared__ unsigned int is_last;
  if (threadIdx.x < 16) {
    int i = threadIdx.x;
    unsigned int klo = __float_as_uint(vp[2 * i]);
    unsigned int khi = __float_as_uint(vp[2 * i + 1]);
    float lo = (float)(klo + 1u) * 0x1p-20f;   // upper boundary of bin (exact)
    float hi = (float)(khi + 1u) * 0x1p-20f;
    float f = fr.f[i];
    float e = lo * (1.0f - f) + hi * f;
    if (i == 15) e += 1e-6f;
    sedge[i] = e;
  }
  __syncthreads();
  float e[16];
#pragma unroll
  for (int j = 0; j < 16; ++j) e[j] = sedge[j];
  float cnt[15], sH[15], sE[15];
#pragma unroll
  for (int b = 0; b < 15; ++b) { cnt[b] = 0.f; sH[b] = 0.f; sE[b] = 0.f; }
  int stride = gridDim.x * blockDim.x;
  for (int i = blockIdx.x * blockDim.x + threadIdx.x; i < n; i += stride) {
    unsigned int kp = keys[i];
    float h = ((float)(kp & KEY_MAX) + 0.5f) * 0x1p-20f;
    float er = (kp & 0x80000000u) ? 1.0f : 0.0f;
    int less = 0;
#pragma unroll
    for (int j = 0; j < 16; ++j) less += (h > e[j]) ? 1 : 0;
    int bin = less - 1;  // valid bins 0..14
#pragma unroll
    for (int b = 0; b < 15; ++b) {
      bool m = (bin == b);
      cnt[b] += m ? 1.f : 0.f;
      sH[b] += m ? h : 0.f;
      sE[b] += m ? er : 0.f;
    }
  }
  int wid = threadIdx.x >> 6;
  int lane = threadIdx.x & 63;
#pragma unroll
  for (int b = 0; b < 15; ++b) {
    float c = cnt[b], a = sH[b], s = sE[b];
    for (int off = 32; off > 0; off >>= 1) {
      c += __shfl_xor(c, off);
      a += __shfl_xor(a, off);
      s += __shfl_xor(s, off);
    }
    if (lane == 0) {
      swacc[wid][b] = c;
      swacc[wid][15 + b] = a;
      swacc[wid][30 + b] = s;
    }
  }
  __syncthreads();
  if (threadIdx.x < 45) {
    int v = threadIdx.x;
    float s = swacc[0][v] + swacc[1][v] + swacc[2][v] + swacc[3][v];
    partials[v * NBIN_BLOCKS + blockIdx.x] = s;
  }
  // ---- last block performs the final reduction ----
  __threadfence();
  if (threadIdx.x == 0)
    is_last = (atomicAdd(done, 1u) == (unsigned int)gridDim.x - 1u) ? 1u : 0u;
  __syncthreads();
  if (is_last && threadIdx.x < 64) {
    __shared__ float sacc[45];
    int l = threadIdx.x;
    for (int v = 0; v < 45; ++v) {
      float s = 0.f;
      for (int b = l; b < NBIN_BLOCKS; b += 64) s += partials[v * NBIN_BLOCKS + b];
      for (int off = 32; off > 0; off >>= 1) s += __shfl_xor(s, off);
      if (l == 0) sacc[v] = s;
    }
    __builtin_amdgcn_s_barrier();  // single wave; harmless
    float g = 0.f;
    if (l < 15) {
      float c = sacc[l], sh = sacc[15 + l], se = sacc[30 + l];
      float safe = fmaxf(c, 1.f);
      float u = sh / safe, eb = se / safe;
      float inner = 2.0f * exp2f(-u) - 1.0f;
      float s = (inner > 0.f) ? sqrtf(inner) : 0.f;
      float risk = 0.5f * (1.0f - s);
      g = (c > 0.f) ? fabsf(eb - risk) : 0.f;
    }
    for (int off = 32; off > 0; off >>= 1) g += __shfl_xor(g, off);
    if (l == 0) out[0] = g * (1.0f / 15.0f);
  }
}

extern "C" void kernel_launch(void* const* d_in, const int* in_sizes, int n_in,
                              void* d_out, int out_size, void* d_ws, size_t ws_size,
                              hipStream_t stream) {
  const float* logits = (const float*)d_in[0];
  const int* labels = (const int*)d_in[1];
  float* out = (float*)d_out;
  int n = in_sizes[1];  // labels count = number of rows

  char* ws = (char*)d_ws;
  size_t offKeys = 0;                                             // n*4
  size_t offHg = (size_t)n * 4;                                   // 1280*4096*4 = 20MB
  size_t offMerged = offHg + (size_t)NH2_BLOCKS * (L1_BINS / 2) * 4;  // 8192*4 (overwritten)
  size_t offH2b = offMerged + (size_t)L1_BINS * 4;                // 32*512*4 (zeroed)
  size_t offDone = offH2b + 32 * L2_BINS * 4;                     // 16 B     (zeroed)
  size_t zeroEnd = offDone + 16;
  size_t offSelP = zeroEnd;                                       // 32*4 (overwritten)
  size_t offSelR = offSelP + 128;                                 // 32*4 (overwritten)
  size_t offV = offSelR + 128;                                    // 32*4 (overwritten)
  size_t offPart = (offV + 128 + 255) & ~(size_t)255;             // 45*NBIN_BLOCKS*4

  unsigned int* keys = (unsigned int*)(ws + offKeys);
  unsigned int* histg = (unsigned int*)(ws + offHg);
  unsigned int* merged = (unsigned int*)(ws + offMerged);
  unsigned int* hist2 = (unsigned int*)(ws + offH2b);
  unsigned int* done = (unsigned int*)(ws + offDone);
  unsigned int* selp = (unsigned int*)(ws + offSelP);
  unsigned int* selr = (unsigned int*)(ws + offSelR);
  float* vp = (float*)(ws + offV);
  float* part = (float*)(ws + offPart);

  // host-side quantile positions (f32, matching jnp.linspace/quantile math)
  Ranks rk;
  Fracs fr;
  float nm1 = (float)(n - 1);
  for (int i = 0; i < 16; ++i) {
    float q = (i == 15) ? 1.0f : (float)i * (1.0f / 15.0f);
    float idxf = q * nm1;
    float flo = floorf(idxf);
    unsigned int klo = (unsigned int)flo;
    unsigned int khi = (unsigned int)ceilf(idxf);
    unsigned int maxi = (unsigned int)(n - 1);
    if (klo > maxi) klo = maxi;
    if (khi > maxi) khi = maxi;
    rk.r[2 * i] = klo;
    rk.r[2 * i + 1] = khi;
    fr.f[i] = idxf - flo;
  }

  // 0) zero hist2 + done counter (~64KB)
  int zero4 = (int)((zeroEnd - offH2b) >> 4);
  k_zero<<<(zero4 + 255) / 256, 256, 0, stream>>>((uint4*)(ws + offH2b), zero4);
  // 1) H2 -> packed keys + per-block L1 hists (plain coalesced stores)
  k_h2<<<NH2_BLOCKS, 256, 0, stream>>>(logits, labels, keys, histg, n);
  // 2) merge per-block hists (256 blocks, tiled LDS reduce)
  k_merge<<<L1_BINS / 2 / 16, 256, 0, stream>>>(histg, merged, NH2_BLOCKS);
  // 3) select L1 bucket (13 bits) for each of 32 ranks
  k_select<<<32, 64, 0, stream>>>(merged, selp, selr, vp, L1_BINS, 0, 0, 0, 1, rk);
  // 4) refine low 9 bits
  k_refine<<<NREF_BLOCKS, 256, 0, stream>>>(keys, selp, hist2, n);
  k_select<<<32, 64, 0, stream>>>(hist2, selp, selr, vp, L2_BINS, 1, 9, 1, 0, rk);
  // 5) binning accumulation + fused final reduction
  k_bin<<<NBIN_BLOCKS, 256, 0, stream>>>(keys, vp, part, done, out, n, fr);

  (void)n_in; (void)out_size; (void)ws_size;
}